// Round 6
// baseline (228.999 us; speedup 1.0000x reference)
//
#include <hip/hip_runtime.h>
#include <cstddef>
#include <cstdint>

#define SEQ 2048
#define DM 1024
#define NH 16
#define HD 64

typedef _Float16 f16;
typedef __attribute__((ext_vector_type(8))) _Float16 f16x8;
typedef __attribute__((ext_vector_type(4))) _Float16 f16x4;
typedef __attribute__((ext_vector_type(2))) _Float16 f16x2;
typedef __attribute__((ext_vector_type(4))) float f32x4;

__global__ __launch_bounds__(256) void cast_kernel(const float* __restrict__ in,
                                                   f16* __restrict__ out, int n4) {
  int i = blockIdx.x * 256 + threadIdx.x;
  if (i < n4) {
    float4 v = ((const float4*)in)[i];
    f16x4 o = {(f16)v.x, (f16)v.y, (f16)v.z, (f16)v.w};
    ((f16x4*)out)[i] = o;
  }
}

// all four 1024x1024 weights in one launch; dst regions are contiguous 2 MB
__global__ __launch_bounds__(256) void cast_w4(const float* __restrict__ Wq,
                                               const float* __restrict__ Wk,
                                               const float* __restrict__ Wv,
                                               const float* __restrict__ Wo,
                                               f16* __restrict__ out) {
  const int i = blockIdx.x * 256 + threadIdx.x;
  const int y = blockIdx.y;
  const float* src = (y == 0) ? Wq : (y == 1) ? Wk : (y == 2) ? Wv : Wo;
  float4 v = ((const float4*)src)[i];
  f16x4 o = {(f16)v.x, (f16)v.y, (f16)v.z, (f16)v.w};
  ((f16x4*)(out + (size_t)y * 1048576))[i] = o;
}

__device__ __forceinline__ void gload16(const void* g, void* lds) {
  __builtin_amdgcn_global_load_lds((const __attribute__((address_space(1))) void*)g,
                                   (__attribute__((address_space(3))) void*)lds,
                                   16, 0, 0);
}

// ---------------------------------------------------------------------------
// f16 GEMM mainloop: C[128,128] tile of A[M,K] @ B[N,K]^T.
// R6: conflict-free LDS image. Staging lane l -> (row = l&15, kchunk = l>>4),
// so the 1 KB per-16-row block is kchunk-major: frag b128 reads span a fully
// contiguous 1 KB -> zero bank conflicts (was 8-way at 64B row stride).
// ---------------------------------------------------------------------------
__device__ __forceinline__ void gemm_tile(const f16* __restrict__ A,
                                          const f16* __restrict__ B,
                                          f16* As, f16* Bs,
                                          int K, f32x4 acc[4][4]) {
  const int t = threadIdx.x;
  const int lane = t & 63;
  const int w = t >> 6;
  const int wm = (w & 1) << 6, wn = (w >> 1) << 6;
  const int fr = lane & 15, q = lane >> 4;
  for (int k0 = 0; k0 < K; k0 += 32) {
    __syncthreads();
#pragma unroll
    for (int c = 0; c < 2; ++c) {
      const int chunk = (w << 1) + c;
      const int row = (chunk << 4) + fr;
      gload16(A + (size_t)row * K + k0 + (q << 3), As + (chunk << 9));
      gload16(B + (size_t)row * K + k0 + (q << 3), Bs + (chunk << 9));
    }
    __syncthreads();
    f16x8 af[4], bfr[4];
#pragma unroll
    for (int i = 0; i < 4; ++i)
      af[i] = *(const f16x8*)(As + (((wm >> 4) + i) << 9) + (q << 7) + (fr << 3));
#pragma unroll
    for (int j = 0; j < 4; ++j)
      bfr[j] = *(const f16x8*)(Bs + (((wn >> 4) + j) << 9) + (q << 7) + (fr << 3));
#pragma unroll
    for (int i = 0; i < 4; ++i)
#pragma unroll
      for (int j = 0; j < 4; ++j)
        acc[i][j] = __builtin_amdgcn_mfma_f32_16x16x32_f16(af[i], bfr[j],
                                                           acc[i][j], 0, 0, 0);
  }
}

// Fused QKV projection. Q pre-scaled by log2(e)/sqrt(d_model) for base-2
// no-max softmax. V stored transposed per head (Vtg[b][h][d][s]) via an
// in-LDS 128x128 transpose (XOR-chunk swizzle) + coalesced f16x8 stores.
#define QSCALE 0.04508422003f /* 1.4426950409/32 */
__global__ __launch_bounds__(256) void gemm_qkv(
    const f16* __restrict__ xb, const f16* __restrict__ Wqb,
    const f16* __restrict__ Wkb, const f16* __restrict__ Wvb,
    f16* __restrict__ Qb, f16* __restrict__ Kb, f16* __restrict__ Vtg) {
  __shared__ f16 smem[16384];  // staging: As[0:4096) Bs[4096:8192); transpose: all
  f16* As = smem;
  f16* Bs = smem + 4096;
  const int which = blockIdx.x >> 3;
  const int bn = (blockIdx.x & 7) << 7;
  const int bm = blockIdx.y << 7;
  const f16* B = (which == 0) ? Wqb : (which == 1) ? Wkb : Wvb;
  f32x4 acc[4][4] = {};
  gemm_tile(xb + (size_t)bm * DM, B + (size_t)bn * DM, As, Bs, DM, acc);
  const int lane = threadIdx.x & 63, w = threadIdx.x >> 6;
  const int wm = (w & 1) << 6, wn = (w >> 1) << 6;
  const int col = lane & 15, q = lane >> 4;
  if (which < 2) {
    f16* C = (which == 0) ? Qb : Kb;
    const float sc = (which == 0) ? QSCALE : 1.0f;
#pragma unroll
    for (int i = 0; i < 4; ++i) {
      const int m = bm + wm + (i << 4) + (q << 2);
#pragma unroll
      for (int j = 0; j < 4; ++j) {
        const int n = bn + wn + (j << 4) + col;
#pragma unroll
        for (int r = 0; r < 4; ++r)
          C[(size_t)(m + r) * DM + n] = (f16)(acc[i][j][r] * sc);
      }
    }
  } else {
    // transpose C-tile in LDS: T[n][m], 128x128 f16, chunk-XOR swizzle
    __syncthreads();  // all waves done with As/Bs MFMA reads
#pragma unroll
    for (int i = 0; i < 4; ++i) {
      const int cm = ((wm + (i << 4)) >> 3) + (q >> 1);
#pragma unroll
      for (int j = 0; j < 4; ++j) {
        const int nl = wn + (j << 4) + col;
        f16x4 o = {(f16)acc[i][j][0], (f16)acc[i][j][1],
                   (f16)acc[i][j][2], (f16)acc[i][j][3]};
        *(f16x4*)(smem + nl * 128 + ((cm ^ (nl & 15)) << 3) + ((q & 1) << 2)) = o;
      }
    }
    __syncthreads();
    const int b = bm >> 11, sbase = bm & 2047;
#pragma unroll
    for (int p = 0; p < 8; ++p) {
      const int nl = p * 16 + w * 4 + (lane >> 4);
      const int cmc = lane & 15;
      const f16x8 v = *(const f16x8*)(smem + nl * 128 + ((cmc ^ (nl & 15)) << 3));
      const int h = (bn + nl) >> 6, d = (bn + nl) & 63;
      *(f16x8*)(Vtg + ((size_t)(b * NH + h) * HD + d) * SEQ + sbase + cmc * 8) = v;
    }
  }
}

__global__ __launch_bounds__(256) void gemm_out(const f16* __restrict__ Ab,
                                                const f16* __restrict__ Wob,
                                                float* __restrict__ out) {
  __shared__ f16 As[128 * 32];
  __shared__ f16 Bs[128 * 32];
  const int bn = blockIdx.x << 7, bm = blockIdx.y << 7;
  f32x4 acc[4][4] = {};
  gemm_tile(Ab + (size_t)bm * DM, Wob + (size_t)bn * DM, As, Bs, DM, acc);
  const int lane = threadIdx.x & 63, w = threadIdx.x >> 6;
  const int wm = (w & 1) << 6, wn = (w >> 1) << 6;
  const int col = lane & 15, q = lane >> 4;
#pragma unroll
  for (int i = 0; i < 4; ++i) {
    const int m = bm + wm + (i << 4) + (q << 2);
#pragma unroll
    for (int j = 0; j < 4; ++j) {
      const int n = bn + wn + (j << 4) + col;
#pragma unroll
      for (int r = 0; r < 4; ++r)
        out[(size_t)(m + r) * DM + n] = acc[i][j][r];
    }
  }
}

// ---------------------------------------------------------------------------
// MFMA flash attention, transposed-score, f16, no-max softmax.
// R6: back to R4's 2-barrier single-buffer K-loop (R5 dbuf regressed: compiler
// orders global_load_lds vs ds_read conservatively). Keep R5's XCD swizzle
// (FETCH 70->12 MB). NEW: conflict-free LDS image — staging lane l ->
// (row = l&15, kchunk = l>>4) makes K b128 frags span a contiguous 1 KB and
// V b64 frags a contiguous 512 B -> zero bank conflicts (was 8-way, ~1.6e7
// conflict-cycles = ~25 us of the 68 us).
// ---------------------------------------------------------------------------
__global__ __launch_bounds__(256) void attn_mfma(const f16* __restrict__ Qb,
                                                 const f16* __restrict__ Kb,
                                                 const f16* __restrict__ Vtg,
                                                 f16* __restrict__ Ctx) {
  __shared__ f16 smem[8192];  // 16 KB: Ks[0:4096) Vs[4096:8192)
  f16* Ks = smem;             // [hf][4 row-blk][kchunk-major 512]
  f16* Vs = smem + 4096;
  const int t = threadIdx.x, lane = t & 63, w = t >> 6;
  const int fr = lane & 15, quad = lane >> 4;
  // XCD-swizzled block mapping: i%8 = XCD; 16 q-tiles of one (b,h) per XCD
  const int i = blockIdx.x;
  const int j = i >> 3;
  const int bh = ((i & 7) << 2) + (j >> 4);
  const int qt16 = j & 15;
  const int b = bh >> 4, h = bh & 15;

  const size_t qrow0 = (size_t)b * SEQ + qt16 * 128 + w * 32;

  // Q^T B-frags, direct from global (loop-invariant): [qt][half]
  f16x8 Qf[2][2];
#pragma unroll
  for (int qt = 0; qt < 2; ++qt)
#pragma unroll
    for (int hf = 0; hf < 2; ++hf)
      Qf[qt][hf] = *(const f16x8*)(Qb + (qrow0 + qt * 16 + fr) * DM + h * HD +
                                   hf * 32 + (quad << 3));

  // staging: wave w covers rows/d 16w..16w+15; lane l -> row fr, kchunk quad
  const f16* Kg = Kb + ((size_t)b * SEQ + 16 * w + fr) * DM + h * HD + (quad << 3);
  const f16* Vg = Vtg + ((size_t)(b * NH + h) * HD + 16 * w + fr) * SEQ + (quad << 3);
  f16* KsW = Ks + (w << 9);
  f16* VsW = Vs + (w << 9);

  f32x4 acc[2][4] = {};  // ctx^T [qt][dtile]
  float lacc[2] = {0.f, 0.f};

  for (int kt = 0; kt < 32; ++kt) {
    const size_t ko = (size_t)kt * 64;
    __syncthreads();  // all waves done reading prev tiles
    gload16(Kg + ko * DM, KsW);              // k-half 0
    gload16(Kg + ko * DM + 32, KsW + 2048);  // k-half 1
    gload16(Vg + ko, VsW);                   // s-half 0
    gload16(Vg + ko + 32, VsW + 2048);       // s-half 1
    __syncthreads();  // vmcnt drained -> LDS visible

    // K A-frags [mtile][half]: contiguous 1 KB per read group, conflict-free
    f16x8 Kf[4][2];
#pragma unroll
    for (int mt = 0; mt < 4; ++mt)
#pragma unroll
      for (int hf = 0; hf < 2; ++hf)
        Kf[mt][hf] = *(const f16x8*)(Ks + hf * 2048 + (mt << 9) + (quad << 7) +
                                     (fr << 3));

    f16x4 pf[2][4];
#pragma unroll
    for (int qt = 0; qt < 2; ++qt) {
      f32x4 z[4] = {};
#pragma unroll
      for (int mt = 0; mt < 4; ++mt) {
        z[mt] = __builtin_amdgcn_mfma_f32_16x16x32_f16(Kf[mt][0], Qf[qt][0],
                                                       z[mt], 0, 0, 0);
        z[mt] = __builtin_amdgcn_mfma_f32_16x16x32_f16(Kf[mt][1], Qf[qt][1],
                                                       z[mt], 0, 0, 0);
      }
#pragma unroll
      for (int mt = 0; mt < 4; ++mt) {
        const float p0 = __builtin_amdgcn_exp2f(z[mt][0]);
        const float p1 = __builtin_amdgcn_exp2f(z[mt][1]);
        const float p2 = __builtin_amdgcn_exp2f(z[mt][2]);
        const float p3 = __builtin_amdgcn_exp2f(z[mt][3]);
        lacc[qt] += (p0 + p1) + (p2 + p3);
        const f16x2 lo = __builtin_bit_cast(f16x2, __builtin_amdgcn_cvt_pkrtz(p0, p1));
        const f16x2 hi = __builtin_bit_cast(f16x2, __builtin_amdgcn_cvt_pkrtz(p2, p3));
        f16x4 pv; pv.x = lo.x; pv.y = lo.y; pv.z = hi.x; pv.w = hi.y;
        pf[qt][mt] = pv;
      }
    }

    // ctx^T += V^T . P^T  (V b64 frags: contiguous 512 B group, conflict-free)
#pragma unroll
    for (int dt = 0; dt < 4; ++dt) {
#pragma unroll
      for (int kc = 0; kc < 4; ++kc) {
        const int c = ((kc & 1) << 1) + (quad >> 1);
        const f16x4 vf = *(const f16x4*)(Vs + (kc >> 1) * 2048 + (dt << 9) +
                                         (c << 7) + (fr << 3) + ((quad & 1) << 2));
#pragma unroll
        for (int qt = 0; qt < 2; ++qt)
          acc[qt][dt] = __builtin_amdgcn_mfma_f32_16x16x16f16(vf, pf[qt][kc],
                                                              acc[qt][dt], 0, 0, 0);
      }
    }
  }

  // l reduction over quads (lanes fr, fr+16, fr+32, fr+48 share a q-col)
  float inv[2];
#pragma unroll
  for (int qt = 0; qt < 2; ++qt) {
    float l = lacc[qt];
    l += __shfl_xor(l, 16);
    l += __shfl_xor(l, 32);
    inv[qt] = __builtin_amdgcn_rcpf(l);
  }

  __syncthreads();  // everyone done with Ks/Vs before epilogue reuse
  f16* T = smem + (w << 11);  // wave-private [32 q][64 d]
#pragma unroll
  for (int qt = 0; qt < 2; ++qt)
#pragma unroll
    for (int dt = 0; dt < 4; ++dt) {
      f16x4 o = {(f16)(acc[qt][dt][0] * inv[qt]), (f16)(acc[qt][dt][1] * inv[qt]),
                 (f16)(acc[qt][dt][2] * inv[qt]), (f16)(acc[qt][dt][3] * inv[qt])};
      *(f16x4*)(T + (qt * 16 + fr) * 64 + dt * 16 + (quad << 2)) = o;
    }
#pragma unroll
  for (int p = 0; p < 4; ++p) {
    const int ql = p * 8 + (lane >> 3);
    const f16x8 v = *(const f16x8*)(T + ql * 64 + ((lane & 7) << 3));
    *(f16x8*)(Ctx + (qrow0 + ql) * DM + h * HD + ((lane & 7) << 3)) = v;
  }
}

extern "C" void kernel_launch(void* const* d_in, const int* in_sizes, int n_in,
                              void* d_out, int out_size, void* d_ws, size_t ws_size,
                              hipStream_t stream) {
  const float* x  = (const float*)d_in[0];
  const float* Wq = (const float*)d_in[1];
  const float* Wk = (const float*)d_in[2];
  const float* Wv = (const float*)d_in[3];
  const float* Wo = (const float*)d_in[4];

  char* ws = (char*)d_ws;
  f16* xb  = (f16*)(ws);                 // 8 MB
  f16* Wb  = (f16*)(ws + (8u << 20));    // 4 x 2 MB contiguous: Wq,Wk,Wv,Wo
  f16* Wqb = Wb;
  f16* Wkb = Wb + 1048576;
  f16* Wvb = Wb + 2097152;
  f16* Wob = Wb + 3145728;
  f16* Qb  = (f16*)(ws + (16u << 20));   // 8 MB (pre-scaled by log2e/32)
  f16* Kb  = (f16*)(ws + (24u << 20));
  f16* Vtg = (f16*)(ws + (32u << 20));   // [b][h][d][s]
  f16* Ctx = (f16*)(ws + (40u << 20));   // -> 48 MB total

  cast_kernel<<<4096, 256, 0, stream>>>(x, xb, 1048576);
  cast_w4<<<dim3(1024, 4), 256, 0, stream>>>(Wq, Wk, Wv, Wo, Wb);

  gemm_qkv<<<dim3(24, 32), 256, 0, stream>>>(xb, Wqb, Wkb, Wvb, Qb, Kb, Vtg);
  attn_mfma<<<dim3(2 * NH * (SEQ / 128)), 256, 0, stream>>>(Qb, Kb, Vtg, Ctx);
  gemm_out<<<dim3(8, 32), 256, 0, stream>>>(Ctx, Wob, (float*)d_out);
}

// Round 8
// 198.652 us; speedup vs baseline: 1.1528x; 1.1528x over previous
//
#include <hip/hip_runtime.h>
#include <cstddef>
#include <cstdint>

#define SEQ 2048
#define DM 1024
#define NH 16
#define HD 64

typedef _Float16 f16;
typedef __attribute__((ext_vector_type(8))) _Float16 f16x8;
typedef __attribute__((ext_vector_type(4))) _Float16 f16x4;
typedef __attribute__((ext_vector_type(2))) _Float16 f16x2;
typedef __attribute__((ext_vector_type(4))) float f32x4;

__global__ __launch_bounds__(256) void cast_kernel(const float* __restrict__ in,
                                                   f16* __restrict__ out, int n4) {
  int i = blockIdx.x * 256 + threadIdx.x;
  if (i < n4) {
    float4 v = ((const float4*)in)[i];
    f16x4 o = {(f16)v.x, (f16)v.y, (f16)v.z, (f16)v.w};
    ((f16x4*)out)[i] = o;
  }
}

// all four 1024x1024 weights in one launch; dst regions are contiguous 2 MB
__global__ __launch_bounds__(256) void cast_w4(const float* __restrict__ Wq,
                                               const float* __restrict__ Wk,
                                               const float* __restrict__ Wv,
                                               const float* __restrict__ Wo,
                                               f16* __restrict__ out) {
  const int i = blockIdx.x * 256 + threadIdx.x;
  const int y = blockIdx.y;
  const float* src = (y == 0) ? Wq : (y == 1) ? Wk : (y == 2) ? Wv : Wo;
  float4 v = ((const float4*)src)[i];
  f16x4 o = {(f16)v.x, (f16)v.y, (f16)v.z, (f16)v.w};
  ((f16x4*)(out + (size_t)y * 1048576))[i] = o;
}

__device__ __forceinline__ void gload16(const void* g, void* lds) {
  __builtin_amdgcn_global_load_lds((const __attribute__((address_space(1))) void*)g,
                                   (__attribute__((address_space(3))) void*)lds,
                                   16, 0, 0);
}

// ---------------------------------------------------------------------------
// f16 GEMM mainloop (m97 structure, R4 version — global side coalesced).
// ---------------------------------------------------------------------------
__device__ __forceinline__ void gemm_tile(const f16* __restrict__ A,
                                          const f16* __restrict__ B,
                                          f16* As, f16* Bs,
                                          int K, f32x4 acc[4][4]) {
  const int t = threadIdx.x;
  const int lane = t & 63;
  const int w = t >> 6;
  const int wm = (w & 1) << 6, wn = (w >> 1) << 6;
  const int srow = lane >> 2, scol = lane & 3;
  const int fr = lane & 15, q = lane >> 4;
  for (int k0 = 0; k0 < K; k0 += 32) {
    __syncthreads();
#pragma unroll
    for (int c = 0; c < 2; ++c) {
      const int chunk = (w << 1) + c;
      const int row = (chunk << 4) + srow;
      gload16(A + (size_t)row * K + k0 + (scol << 3), As + (chunk << 9));
      gload16(B + (size_t)row * K + k0 + (scol << 3), Bs + (chunk << 9));
    }
    __syncthreads();
    f16x8 af[4], bfr[4];
#pragma unroll
    for (int i = 0; i < 4; ++i)
      af[i] = *(const f16x8*)(As + (wm + (i << 4) + fr) * 32 + (q << 3));
#pragma unroll
    for (int j = 0; j < 4; ++j)
      bfr[j] = *(const f16x8*)(Bs + (wn + (j << 4) + fr) * 32 + (q << 3));
#pragma unroll
    for (int i = 0; i < 4; ++i)
#pragma unroll
      for (int j = 0; j < 4; ++j)
        acc[i][j] = __builtin_amdgcn_mfma_f32_16x16x32_f16(af[i], bfr[j],
                                                           acc[i][j], 0, 0, 0);
  }
}

// Fused QKV projection. Q pre-scaled by log2(e)/sqrt(d_model).
// V stored in MFMA-native frag layout (R8 FIX: per-tile 4096, per-bh 131072):
//   flat(d, s) = bh*131072 + (s>>6)*4096 + ((s>>2)&15)*256 + d*4 + (s&3)
// so attention V A-frags are direct coalesced 8B/lane global reads (no LDS).
#define QSCALE 0.04508422003f /* 1.4426950409/32 */
__global__ __launch_bounds__(256) void gemm_qkv(
    const f16* __restrict__ xb, const f16* __restrict__ Wqb,
    const f16* __restrict__ Wkb, const f16* __restrict__ Wvb,
    f16* __restrict__ Qb, f16* __restrict__ Kb, f16* __restrict__ Vtg) {
  __shared__ f16 smem[16384];  // staging As/Bs in first 16KB; transpose uses all
  f16* As = smem;
  f16* Bs = smem + 4096;
  const int which = blockIdx.x >> 3;
  const int bn = (blockIdx.x & 7) << 7;
  const int bm = blockIdx.y << 7;
  const f16* B = (which == 0) ? Wqb : (which == 1) ? Wkb : Wvb;
  f32x4 acc[4][4] = {};
  gemm_tile(xb + (size_t)bm * DM, B + (size_t)bn * DM, As, Bs, DM, acc);
  const int lane = threadIdx.x & 63, w = threadIdx.x >> 6;
  const int wm = (w & 1) << 6, wn = (w >> 1) << 6;
  const int col = lane & 15, q = lane >> 4;
  if (which < 2) {
    f16* C = (which == 0) ? Qb : Kb;
    const float sc = (which == 0) ? QSCALE : 1.0f;
#pragma unroll
    for (int i = 0; i < 4; ++i) {
      const int m = bm + wm + (i << 4) + (q << 2);
#pragma unroll
      for (int j = 0; j < 4; ++j) {
        const int n = bn + wn + (j << 4) + col;
#pragma unroll
        for (int r = 0; r < 4; ++r)
          C[(size_t)(m + r) * DM + n] = (f16)(acc[i][j][r] * sc);
      }
    }
  } else {
    // LDS transpose T[nl][m] (swizzled chunks), then frag-layout global stores.
    __syncthreads();  // all waves done with As/Bs MFMA reads
#pragma unroll
    for (int i = 0; i < 4; ++i) {
      const int m0 = wm + (i << 4) + (q << 2);
      const int cm = m0 >> 3, sub = (m0 >> 2) & 1;
#pragma unroll
      for (int j = 0; j < 4; ++j) {
        const int nl = wn + (j << 4) + col;
        f16x4 o = {(f16)acc[i][j][0], (f16)acc[i][j][1],
                   (f16)acc[i][j][2], (f16)acc[i][j][3]};
        *(f16x4*)(smem + nl * 128 +
                  ((cm ^ (nl & 15) ^ ((nl >> 4) & 3)) << 3) + (sub << 2)) = o;
      }
    }
    __syncthreads();
    const int b = bm >> 11, sb = bm & 2047;  // sb multiple of 128
    const int d = threadIdx.x & 63;
#pragma unroll
    for (int step = 0; step < 16; ++step) {
      const int idx = (threadIdx.x >> 6) + (step << 2);  // 0..63
      const int hh = idx >> 5, s4 = idx & 31;
      const int nl = (hh << 6) + d;
      const int cm = s4 >> 1, sub = s4 & 1;
      const f16x4 v = *(const f16x4*)(smem + nl * 128 +
                                      ((cm ^ (nl & 15) ^ ((nl >> 4) & 3)) << 3) +
                                      (sub << 2));
      const int bh = (b << 4) + (bn >> 6) + hh;
      const int sg = sb + (s4 << 2);
      const size_t flat = ((size_t)bh << 17) + ((size_t)(sg >> 6) << 12) +
                          ((s4 & 15) << 8) + (d << 2);
      *(f16x4*)(Vtg + flat) = v;
    }
  }
}

__global__ __launch_bounds__(256) void gemm_out(const f16* __restrict__ Ab,
                                                const f16* __restrict__ Wob,
                                                float* __restrict__ out) {
  __shared__ f16 As[128 * 32];
  __shared__ f16 Bs[128 * 32];
  const int bn = blockIdx.x << 7, bm = blockIdx.y << 7;
  f32x4 acc[4][4] = {};
  gemm_tile(Ab + (size_t)bm * DM, Wob + (size_t)bn * DM, As, Bs, DM, acc);
  const int lane = threadIdx.x & 63, w = threadIdx.x >> 6;
  const int wm = (w & 1) << 6, wn = (w >> 1) << 6;
  const int col = lane & 15, q = lane >> 4;
#pragma unroll
  for (int i = 0; i < 4; ++i) {
    const int m = bm + wm + (i << 4) + (q << 2);
#pragma unroll
    for (int j = 0; j < 4; ++j) {
      const int n = bn + wn + (j << 4) + col;
#pragma unroll
      for (int r = 0; r < 4; ++r)
        out[(size_t)(m + r) * DM + n] = acc[i][j][r];
    }
  }
}

// ---------------------------------------------------------------------------
// MFMA flash attention R8 (= R7 with corrected Vtg strides).
//  - K: global->regs (coalesced dwordx4) -> ds_write into chunk-permuted
//    image; both ds_write and b128 frag reads hit each 4-bank group with the
//    structural-minimum 8 lanes -> no excess conflicts.
//  - V: registers only (frag-layout Vtg, coalesced 8B/lane), no LDS.
//  - XCD swizzle kept (K/V L2-resident per XCD).
// ---------------------------------------------------------------------------
__global__ __launch_bounds__(256, 2) void attn_mfma(const f16* __restrict__ Qb,
                                                    const f16* __restrict__ Kb,
                                                    const f16* __restrict__ Vtg,
                                                    f16* __restrict__ Ctx) {
  __shared__ f16 smem[8192];  // 16 KB: K tile in [0:4096); epilogue T uses all
  const int t = threadIdx.x, lane = t & 63, w = t >> 6;
  const int fr = lane & 15, quad = lane >> 4;
  const int i = blockIdx.x;
  const int j = i >> 3;
  const int bh = ((i & 7) << 2) + (j >> 4);
  const int qt16 = j & 15;
  const int b = bh >> 4, h = bh & 15;

  const size_t qrow0 = (size_t)b * SEQ + qt16 * 128 + w * 32;

  // Q^T B-frags, loop-invariant
  f16x8 Qf[2][2];
#pragma unroll
  for (int qt = 0; qt < 2; ++qt)
#pragma unroll
    for (int hf = 0; hf < 2; ++hf)
      Qf[qt][hf] = *(const f16x8*)(Qb + (qrow0 + qt * 16 + fr) * DM + h * HD +
                                   hf * 32 + (quad << 3));

  // K reg-staging: lane -> (row16 = lane>>2, kc = lane&3), wave w rows 16w..+15
  const int krow = lane >> 2, kkc = lane & 3;
  const f16* Kg = Kb + ((size_t)b * SEQ + 16 * w + krow) * DM + h * HD + (kkc << 3);
  const int cwr = ((krow >> 1) << 3) | ((krow & 1) << 2) | (((krow >> 1) + kkc) & 3);
  f16* KsW = smem + (w << 9) + (cwr << 3);
  const int crd = ((fr >> 1) << 3) | ((fr & 1) << 2) | (((fr >> 1) + quad) & 3);
  const f16* KsR = smem + (crd << 3);

  // V frag-layout source (R8: bh stride 131072, tile stride 4096)
  const f16* Vg = Vtg + ((size_t)bh << 17) + (quad << 8) + (fr << 2);

  f16x8 kreg[2];
  f16x4 vreg[4][4];
  auto loadK = [&](int kt) {
#pragma unroll
    for (int hf = 0; hf < 2; ++hf)
      kreg[hf] = *(const f16x8*)(Kg + (size_t)kt * 64 * DM + hf * 32);
  };
  auto loadV = [&](int kt) {
#pragma unroll
    for (int kc = 0; kc < 4; ++kc)
#pragma unroll
      for (int dt = 0; dt < 4; ++dt)
        vreg[dt][kc] = *(const f16x4*)(Vg + kt * 4096 + (kc << 10) + (dt << 6));
  };

  loadK(0);
  loadV(0);
  f32x4 acc[2][4] = {};
  float lacc[2] = {0.f, 0.f};

  for (int kt = 0; kt < 32; ++kt) {
    __syncthreads();            // waves done reading K image of tile kt-1
    *(f16x8*)(KsW) = kreg[0];   // hf 0  (vmcnt wait on kreg: issued 1 iter ago)
    *(f16x8*)(KsW + 2048) = kreg[1];
    __syncthreads();            // K tile kt published
    if (kt < 31) loadK(kt + 1); // latency spans the whole compute phase below

    f16x8 Kf[4][2];
#pragma unroll
    for (int mt = 0; mt < 4; ++mt)
#pragma unroll
      for (int hf = 0; hf < 2; ++hf)
        Kf[mt][hf] = *(const f16x8*)(KsR + hf * 2048 + (mt << 9));

    f16x4 pf[2][4];
#pragma unroll
    for (int qt = 0; qt < 2; ++qt) {
      f32x4 z[4] = {};
#pragma unroll
      for (int mt = 0; mt < 4; ++mt) {
        z[mt] = __builtin_amdgcn_mfma_f32_16x16x32_f16(Kf[mt][0], Qf[qt][0],
                                                       z[mt], 0, 0, 0);
        z[mt] = __builtin_amdgcn_mfma_f32_16x16x32_f16(Kf[mt][1], Qf[qt][1],
                                                       z[mt], 0, 0, 0);
      }
#pragma unroll
      for (int mt = 0; mt < 4; ++mt) {
        const float p0 = __builtin_amdgcn_exp2f(z[mt][0]);
        const float p1 = __builtin_amdgcn_exp2f(z[mt][1]);
        const float p2 = __builtin_amdgcn_exp2f(z[mt][2]);
        const float p3 = __builtin_amdgcn_exp2f(z[mt][3]);
        lacc[qt] += (p0 + p1) + (p2 + p3);
        const f16x2 lo = __builtin_bit_cast(f16x2, __builtin_amdgcn_cvt_pkrtz(p0, p1));
        const f16x2 hi = __builtin_bit_cast(f16x2, __builtin_amdgcn_cvt_pkrtz(p2, p3));
        f16x4 pv; pv.x = lo.x; pv.y = lo.y; pv.z = hi.x; pv.w = hi.y;
        pf[qt][mt] = pv;
      }
    }

    // ctx^T += V^T . P^T   (V from registers)
#pragma unroll
    for (int dt = 0; dt < 4; ++dt)
#pragma unroll
      for (int kc = 0; kc < 4; ++kc)
#pragma unroll
        for (int qt = 0; qt < 2; ++qt)
          acc[qt][dt] = __builtin_amdgcn_mfma_f32_16x16x16f16(vreg[dt][kc],
                                                              pf[qt][kc],
                                                              acc[qt][dt], 0, 0, 0);
    if (kt < 31) loadV(kt + 1);  // after PV consumed vreg
  }

  // l reduction over quads (lanes fr, fr+16, fr+32, fr+48 share a q-col)
  float inv[2];
#pragma unroll
  for (int qt = 0; qt < 2; ++qt) {
    float l = lacc[qt];
    l += __shfl_xor(l, 16);
    l += __shfl_xor(l, 32);
    inv[qt] = __builtin_amdgcn_rcpf(l);
  }

  __syncthreads();  // done with K image before epilogue reuse
  f16* T = smem + (w << 11);  // wave-private [32 q][64 d]
#pragma unroll
  for (int qt = 0; qt < 2; ++qt)
#pragma unroll
    for (int dt = 0; dt < 4; ++dt) {
      f16x4 o = {(f16)(acc[qt][dt][0] * inv[qt]), (f16)(acc[qt][dt][1] * inv[qt]),
                 (f16)(acc[qt][dt][2] * inv[qt]), (f16)(acc[qt][dt][3] * inv[qt])};
      *(f16x4*)(T + (qt * 16 + fr) * 64 + dt * 16 + (quad << 2)) = o;
    }
#pragma unroll
  for (int p = 0; p < 4; ++p) {
    const int ql = p * 8 + (lane >> 3);
    const f16x8 v = *(const f16x8*)(T + ql * 64 + ((lane & 7) << 3));
    *(f16x8*)(Ctx + (qrow0 + ql) * DM + h * HD + ((lane & 7) << 3)) = v;
  }
}

extern "C" void kernel_launch(void* const* d_in, const int* in_sizes, int n_in,
                              void* d_out, int out_size, void* d_ws, size_t ws_size,
                              hipStream_t stream) {
  const float* x  = (const float*)d_in[0];
  const float* Wq = (const float*)d_in[1];
  const float* Wk = (const float*)d_in[2];
  const float* Wv = (const float*)d_in[3];
  const float* Wo = (const float*)d_in[4];

  char* ws = (char*)d_ws;
  f16* xb  = (f16*)(ws);                 // 8 MB
  f16* Wb  = (f16*)(ws + (8u << 20));    // 4 x 2 MB contiguous: Wq,Wk,Wv,Wo
  f16* Wqb = Wb;
  f16* Wkb = Wb + 1048576;
  f16* Wvb = Wb + 2097152;
  f16* Wob = Wb + 3145728;
  f16* Qb  = (f16*)(ws + (16u << 20));   // 8 MB (pre-scaled by log2e/32)
  f16* Kb  = (f16*)(ws + (24u << 20));
  f16* Vtg = (f16*)(ws + (32u << 20));   // frag-layout V, 8 MB
  f16* Ctx = (f16*)(ws + (40u << 20));   // -> 48 MB total

  cast_kernel<<<4096, 256, 0, stream>>>(x, xb, 1048576);
  cast_w4<<<dim3(1024, 4), 256, 0, stream>>>(Wq, Wk, Wv, Wo, Wb);

  gemm_qkv<<<dim3(24, 32), 256, 0, stream>>>(xb, Wqb, Wkb, Wvb, Qb, Kb, Vtg);
  attn_mfma<<<dim3(2 * NH * (SEQ / 128)), 256, 0, stream>>>(Qb, Kb, Vtg, Ctx);
  gemm_out<<<dim3(8, 32), 256, 0, stream>>>(Ctx, Wob, (float*)d_out);
}

// Round 9
// 192.625 us; speedup vs baseline: 1.1888x; 1.0313x over previous
//
#include <hip/hip_runtime.h>
#include <cstddef>
#include <cstdint>

#define SEQ 2048
#define DM 1024
#define NH 16
#define HD 64

typedef _Float16 f16;
typedef __attribute__((ext_vector_type(8))) _Float16 f16x8;
typedef __attribute__((ext_vector_type(4))) _Float16 f16x4;
typedef __attribute__((ext_vector_type(2))) _Float16 f16x2;
typedef __attribute__((ext_vector_type(4))) float f32x4;

// one launch: cast x (1M float4) + 4 weights (256K float4 each) into the
// contiguous 16 MB f16 region [xb | Wq | Wk | Wv | Wo]
__global__ __launch_bounds__(256) void cast_all(const float* __restrict__ x,
                                                const float* __restrict__ Wq,
                                                const float* __restrict__ Wk,
                                                const float* __restrict__ Wv,
                                                const float* __restrict__ Wo,
                                                f16* __restrict__ dst) {
  const int i = blockIdx.x * 256 + threadIdx.x;  // float4 index, 2M total
  const float* src;
  int off;
  if (i < 1048576) {
    src = x; off = i;
  } else {
    const int j = i - 1048576;
    const int wsel = j >> 18;
    src = (wsel == 0) ? Wq : (wsel == 1) ? Wk : (wsel == 2) ? Wv : Wo;
    off = j & 262143;
  }
  const float4 v = ((const float4*)src)[off];
  f16x4 o = {(f16)v.x, (f16)v.y, (f16)v.z, (f16)v.w};
  ((f16x4*)dst)[i] = o;
}

__device__ __forceinline__ void gload16(const void* g, void* lds) {
  __builtin_amdgcn_global_load_lds((const __attribute__((address_space(1))) void*)g,
                                   (__attribute__((address_space(3))) void*)lds,
                                   16, 0, 0);
}

// ---------------------------------------------------------------------------
// f16 GEMM mainloop (m97 structure).
// ---------------------------------------------------------------------------
__device__ __forceinline__ void gemm_tile(const f16* __restrict__ A,
                                          const f16* __restrict__ B,
                                          f16* As, f16* Bs,
                                          int K, f32x4 acc[4][4]) {
  const int t = threadIdx.x;
  const int lane = t & 63;
  const int w = t >> 6;
  const int wm = (w & 1) << 6, wn = (w >> 1) << 6;
  const int srow = lane >> 2, scol = lane & 3;
  const int fr = lane & 15, q = lane >> 4;
  for (int k0 = 0; k0 < K; k0 += 32) {
    __syncthreads();
#pragma unroll
    for (int c = 0; c < 2; ++c) {
      const int chunk = (w << 1) + c;
      const int row = (chunk << 4) + srow;
      gload16(A + (size_t)row * K + k0 + (scol << 3), As + (chunk << 9));
      gload16(B + (size_t)row * K + k0 + (scol << 3), Bs + (chunk << 9));
    }
    __syncthreads();
    f16x8 af[4], bfr[4];
#pragma unroll
    for (int i = 0; i < 4; ++i)
      af[i] = *(const f16x8*)(As + (wm + (i << 4) + fr) * 32 + (q << 3));
#pragma unroll
    for (int j = 0; j < 4; ++j)
      bfr[j] = *(const f16x8*)(Bs + (wn + (j << 4) + fr) * 32 + (q << 3));
#pragma unroll
    for (int i = 0; i < 4; ++i)
#pragma unroll
      for (int j = 0; j < 4; ++j)
        acc[i][j] = __builtin_amdgcn_mfma_f32_16x16x32_f16(af[i], bfr[j],
                                                           acc[i][j], 0, 0, 0);
  }
}

// Fused QKV projection. Q pre-scaled by log2(e)/sqrt(d_model).
// V stored in MFMA-native frag layout:
//   flat(d, s) = bh*131072 + (s>>6)*4096 + ((s>>2)&15)*256 + d*4 + (s&3)
#define QSCALE 0.04508422003f /* 1.4426950409/32 */
__global__ __launch_bounds__(256) void gemm_qkv(
    const f16* __restrict__ xb, const f16* __restrict__ Wqb,
    const f16* __restrict__ Wkb, const f16* __restrict__ Wvb,
    f16* __restrict__ Qb, f16* __restrict__ Kb, f16* __restrict__ Vtg) {
  __shared__ f16 smem[16384];
  f16* As = smem;
  f16* Bs = smem + 4096;
  const int which = blockIdx.x >> 3;
  const int bn = (blockIdx.x & 7) << 7;
  const int bm = blockIdx.y << 7;
  const f16* B = (which == 0) ? Wqb : (which == 1) ? Wkb : Wvb;
  f32x4 acc[4][4] = {};
  gemm_tile(xb + (size_t)bm * DM, B + (size_t)bn * DM, As, Bs, DM, acc);
  const int lane = threadIdx.x & 63, w = threadIdx.x >> 6;
  const int wm = (w & 1) << 6, wn = (w >> 1) << 6;
  const int col = lane & 15, q = lane >> 4;
  if (which < 2) {
    f16* C = (which == 0) ? Qb : Kb;
    const float sc = (which == 0) ? QSCALE : 1.0f;
#pragma unroll
    for (int i = 0; i < 4; ++i) {
      const int m = bm + wm + (i << 4) + (q << 2);
#pragma unroll
      for (int j = 0; j < 4; ++j) {
        const int n = bn + wn + (j << 4) + col;
#pragma unroll
        for (int r = 0; r < 4; ++r)
          C[(size_t)(m + r) * DM + n] = (f16)(acc[i][j][r] * sc);
      }
    }
  } else {
    // LDS transpose T[nl][m] (swizzled chunks), then frag-layout global stores.
    __syncthreads();
#pragma unroll
    for (int i = 0; i < 4; ++i) {
      const int m0 = wm + (i << 4) + (q << 2);
      const int cm = m0 >> 3, sub = (m0 >> 2) & 1;
#pragma unroll
      for (int j = 0; j < 4; ++j) {
        const int nl = wn + (j << 4) + col;
        f16x4 o = {(f16)acc[i][j][0], (f16)acc[i][j][1],
                   (f16)acc[i][j][2], (f16)acc[i][j][3]};
        *(f16x4*)(smem + nl * 128 +
                  ((cm ^ (nl & 15) ^ ((nl >> 4) & 3)) << 3) + (sub << 2)) = o;
      }
    }
    __syncthreads();
    const int b = bm >> 11, sb = bm & 2047;
    const int d = threadIdx.x & 63;
#pragma unroll
    for (int step = 0; step < 16; ++step) {
      const int idx = (threadIdx.x >> 6) + (step << 2);  // 0..63
      const int hh = idx >> 5, s4 = idx & 31;
      const int nl = (hh << 6) + d;
      const int cm = s4 >> 1, sub = s4 & 1;
      const f16x4 v = *(const f16x4*)(smem + nl * 128 +
                                      ((cm ^ (nl & 15) ^ ((nl >> 4) & 3)) << 3) +
                                      (sub << 2));
      const int bh = (b << 4) + (bn >> 6) + hh;
      const int sg = sb + (s4 << 2);
      const size_t flat = ((size_t)bh << 17) + ((size_t)(sg >> 6) << 12) +
                          ((s4 & 15) << 8) + (d << 2);
      *(f16x4*)(Vtg + flat) = v;
    }
  }
}

__global__ __launch_bounds__(256) void gemm_out(const f16* __restrict__ Ab,
                                                const f16* __restrict__ Wob,
                                                float* __restrict__ out) {
  __shared__ f16 As[128 * 32];
  __shared__ f16 Bs[128 * 32];
  const int bn = blockIdx.x << 7, bm = blockIdx.y << 7;
  f32x4 acc[4][4] = {};
  gemm_tile(Ab + (size_t)bm * DM, Wob + (size_t)bn * DM, As, Bs, DM, acc);
  const int lane = threadIdx.x & 63, w = threadIdx.x >> 6;
  const int wm = (w & 1) << 6, wn = (w >> 1) << 6;
  const int col = lane & 15, q = lane >> 4;
#pragma unroll
  for (int i = 0; i < 4; ++i) {
    const int m = bm + wm + (i << 4) + (q << 2);
#pragma unroll
    for (int j = 0; j < 4; ++j) {
      const int n = bn + wn + (j << 4) + col;
#pragma unroll
      for (int r = 0; r < 4; ++r)
        out[(size_t)(m + r) * DM + n] = acc[i][j][r];
    }
  }
}

// ---------------------------------------------------------------------------
// MFMA flash attention R9: one barrier per kt, all prefetch covered.
//  - K LDS image double-buffered (2 x 8 KB): barrier publishes img[cur];
//    next tile's ds_write targets img[nxt] at end of body.
//  - V regs double-buffered: loadV(kt+1) issues right after the barrier,
//    PV consumes vbuf[cur] -> the vmcnt(0) drain at the next barrier lands a
//    full compute phase after issue (fixes R8's zero-cover V prefetch).
//  - Loop 2x-unrolled so buffer indices are compile-time (no scratch).
// ---------------------------------------------------------------------------
__global__ __launch_bounds__(256, 2) void attn_mfma(const f16* __restrict__ Qb,
                                                    const f16* __restrict__ Kb,
                                                    const f16* __restrict__ Vtg,
                                                    f16* __restrict__ Ctx) {
  __shared__ f16 smem[8192];  // 16 KB: K img0 [0:4096) | img1 [4096:8192)
  const int t = threadIdx.x, lane = t & 63, w = t >> 6;
  const int fr = lane & 15, quad = lane >> 4;
  const int i = blockIdx.x;
  const int j = i >> 3;
  const int bh = ((i & 7) << 2) + (j >> 4);
  const int qt16 = j & 15;
  const int b = bh >> 4, h = bh & 15;

  const size_t qrow0 = (size_t)b * SEQ + qt16 * 128 + w * 32;

  // Q^T B-frags, loop-invariant
  f16x8 Qf[2][2];
#pragma unroll
  for (int qt = 0; qt < 2; ++qt)
#pragma unroll
    for (int hf = 0; hf < 2; ++hf)
      Qf[qt][hf] = *(const f16x8*)(Qb + (qrow0 + qt * 16 + fr) * DM + h * HD +
                                   hf * 32 + (quad << 3));

  // K reg-staging: lane -> (row16 = lane>>2, kc = lane&3), wave w rows 16w..+15
  const int krow = lane >> 2, kkc = lane & 3;
  const f16* Kg = Kb + ((size_t)b * SEQ + 16 * w + krow) * DM + h * HD + (kkc << 3);
  const int cwr = ((krow >> 1) << 3) | ((krow & 1) << 2) | (((krow >> 1) + kkc) & 3);
  const int wofs = (w << 9) + (cwr << 3);
  const int crd = ((fr >> 1) << 3) | ((fr & 1) << 2) | (((fr >> 1) + quad) & 3);

  // V frag-layout source (bh stride 131072, tile stride 4096)
  const f16* Vg = Vtg + ((size_t)bh << 17) + (quad << 8) + (fr << 2);

  f16x8 kreg[2];
  f16x4 va[4][4], vb[4][4];
  auto loadK = [&](int kt) {
#pragma unroll
    for (int hf = 0; hf < 2; ++hf)
      kreg[hf] = *(const f16x8*)(Kg + (size_t)kt * 64 * DM + hf * 32);
  };
  auto loadV = [&](int kt, f16x4 (&vr)[4][4]) {
#pragma unroll
    for (int kc = 0; kc < 4; ++kc)
#pragma unroll
      for (int dt = 0; dt < 4; ++dt)
        vr[dt][kc] = *(const f16x4*)(Vg + kt * 4096 + (kc << 10) + (dt << 6));
  };

  f32x4 acc[2][4] = {};
  float lacc[2] = {0.f, 0.f};

  f16* img0 = smem;
  f16* img1 = smem + 4096;

  loadK(0);
  loadV(0, va);
  *(f16x8*)(img0 + wofs) = kreg[0];          // vmcnt wait on kreg (once)
  *(f16x8*)(img0 + wofs + 2048) = kreg[1];

  auto body = [&](int kt, f16x4 (&vcur)[4][4], f16x4 (&vnxt)[4][4],
                  f16* imgR, f16* imgW) {
    __syncthreads();  // publishes imgR (tile kt); drains loads issued last body
    if (kt < 31) {
      loadK(kt + 1);
      loadV(kt + 1, vnxt);
    }
    f16x8 Kf[4][2];
#pragma unroll
    for (int mt = 0; mt < 4; ++mt)
#pragma unroll
      for (int hf = 0; hf < 2; ++hf)
        Kf[mt][hf] = *(const f16x8*)(imgR + (crd << 3) + hf * 2048 + (mt << 9));

    f16x4 pf[2][4];
#pragma unroll
    for (int qt = 0; qt < 2; ++qt) {
      f32x4 z[4] = {};
#pragma unroll
      for (int mt = 0; mt < 4; ++mt) {
        z[mt] = __builtin_amdgcn_mfma_f32_16x16x32_f16(Kf[mt][0], Qf[qt][0],
                                                       z[mt], 0, 0, 0);
        z[mt] = __builtin_amdgcn_mfma_f32_16x16x32_f16(Kf[mt][1], Qf[qt][1],
                                                       z[mt], 0, 0, 0);
      }
#pragma unroll
      for (int mt = 0; mt < 4; ++mt) {
        const float p0 = __builtin_amdgcn_exp2f(z[mt][0]);
        const float p1 = __builtin_amdgcn_exp2f(z[mt][1]);
        const float p2 = __builtin_amdgcn_exp2f(z[mt][2]);
        const float p3 = __builtin_amdgcn_exp2f(z[mt][3]);
        lacc[qt] += (p0 + p1) + (p2 + p3);
        const f16x2 lo = __builtin_bit_cast(f16x2, __builtin_amdgcn_cvt_pkrtz(p0, p1));
        const f16x2 hi = __builtin_bit_cast(f16x2, __builtin_amdgcn_cvt_pkrtz(p2, p3));
        f16x4 pv; pv.x = lo.x; pv.y = lo.y; pv.z = hi.x; pv.w = hi.y;
        pf[qt][mt] = pv;
      }
    }

#pragma unroll
    for (int dt = 0; dt < 4; ++dt)
#pragma unroll
      for (int kc = 0; kc < 4; ++kc)
#pragma unroll
        for (int qt = 0; qt < 2; ++qt)
          acc[qt][dt] = __builtin_amdgcn_mfma_f32_16x16x16f16(vcur[dt][kc],
                                                              pf[qt][kc],
                                                              acc[qt][dt], 0, 0, 0);
    if (kt < 31) {
      // write tile kt+1 into the other image (its readers finished before the
      // barrier at the top of this body). vmcnt wait on kreg covered by compute.
      *(f16x8*)(imgW + wofs) = kreg[0];
      *(f16x8*)(imgW + wofs + 2048) = kreg[1];
    }
  };

  for (int kt = 0; kt < 32; kt += 2) {
    body(kt, va, vb, img0, img1);
    body(kt + 1, vb, va, img1, img0);
  }

  // l reduction over quads (lanes fr, fr+16, fr+32, fr+48 share a q-col)
  float inv[2];
#pragma unroll
  for (int qt = 0; qt < 2; ++qt) {
    float l = lacc[qt];
    l += __shfl_xor(l, 16);
    l += __shfl_xor(l, 32);
    inv[qt] = __builtin_amdgcn_rcpf(l);
  }

  __syncthreads();  // done with K images before epilogue reuse
  f16* T = smem + (w << 11);  // wave-private [32 q][64 d]
#pragma unroll
  for (int qt = 0; qt < 2; ++qt)
#pragma unroll
    for (int dt = 0; dt < 4; ++dt) {
      f16x4 o = {(f16)(acc[qt][dt][0] * inv[qt]), (f16)(acc[qt][dt][1] * inv[qt]),
                 (f16)(acc[qt][dt][2] * inv[qt]), (f16)(acc[qt][dt][3] * inv[qt])};
      *(f16x4*)(T + (qt * 16 + fr) * 64 + dt * 16 + (quad << 2)) = o;
    }
#pragma unroll
  for (int p = 0; p < 4; ++p) {
    const int ql = p * 8 + (lane >> 3);
    const f16x8 v = *(const f16x8*)(T + ql * 64 + ((lane & 7) << 3));
    *(f16x8*)(Ctx + (qrow0 + ql) * DM + h * HD + ((lane & 7) << 3)) = v;
  }
}

extern "C" void kernel_launch(void* const* d_in, const int* in_sizes, int n_in,
                              void* d_out, int out_size, void* d_ws, size_t ws_size,
                              hipStream_t stream) {
  const float* x  = (const float*)d_in[0];
  const float* Wq = (const float*)d_in[1];
  const float* Wk = (const float*)d_in[2];
  const float* Wv = (const float*)d_in[3];
  const float* Wo = (const float*)d_in[4];

  char* ws = (char*)d_ws;
  f16* xb  = (f16*)(ws);                 // 8 MB; Wb contiguous after it
  f16* Wb  = (f16*)(ws + (8u << 20));    // 4 x 2 MB: Wq,Wk,Wv,Wo
  f16* Wqb = Wb;
  f16* Wkb = Wb + 1048576;
  f16* Wvb = Wb + 2097152;
  f16* Wob = Wb + 3145728;
  f16* Qb  = (f16*)(ws + (16u << 20));   // 8 MB (pre-scaled by log2e/32)
  f16* Kb  = (f16*)(ws + (24u << 20));
  f16* Vtg = (f16*)(ws + (32u << 20));   // frag-layout V, 8 MB
  f16* Ctx = (f16*)(ws + (40u << 20));   // -> 48 MB total

  cast_all<<<8192, 256, 0, stream>>>(x, Wq, Wk, Wv, Wo, xb);

  gemm_qkv<<<dim3(24, 32), 256, 0, stream>>>(xb, Wqb, Wkb, Wvb, Qb, Kb, Vtg);
  attn_mfma<<<dim3(2 * NH * (SEQ / 128)), 256, 0, stream>>>(Qb, Kb, Vtg, Ctx);
  gemm_out<<<dim3(8, 32), 256, 0, stream>>>(Ctx, Wob, (float*)d_out);
}